// Round 14
// baseline (613.638 us; speedup 1.0000x reference)
//
#include <hip/hip_runtime.h>
#include <hip/hip_bf16.h>

#define NN 100000
#define NE 3200000
#define IN_F 512
#define NH 64
#define NC 16
#define K_HOPS 10

#define BSPAN 256
#define NBUCKC ((NN + BSPAN - 1) / BSPAN)   // 391
#define NPOS (NBUCKC * BSPAN)               // 100096
#define NBUCKP 512
#define CAP 9216
#define PART_BLOCKS 256
#define PCHUNK ((NE + PART_BLOCKS - 1) / PART_BLOCKS)  // 12500

typedef short bf16x8 __attribute__((ext_vector_type(8)));
typedef float f32x4 __attribute__((ext_vector_type(4)));
typedef int   i32x4 __attribute__((ext_vector_type(4)));
typedef unsigned short u16;
typedef u16 u16x4 __attribute__((ext_vector_type(4)));

__device__ __forceinline__ short f2bf_s(float x) {
    __hip_bfloat16 b = __float2bfloat16(x);
    return *reinterpret_cast<short*>(&b);
}
__device__ __forceinline__ float bf2f_s(short s) {
    __hip_bfloat16 b = *reinterpret_cast<__hip_bfloat16*>(&s);
    return __bfloat162float(b);
}
__device__ __forceinline__ float bf2f_u(u16 s) {
    return __uint_as_float((unsigned)s << 16);
}
__device__ __forceinline__ f32x4 bf4_to_f32(u16x4 v) {
    f32x4 r;
    r[0] = __uint_as_float((unsigned)v[0] << 16);
    r[1] = __uint_as_float((unsigned)v[1] << 16);
    r[2] = __uint_as_float((unsigned)v[2] << 16);
    r[3] = __uint_as_float((unsigned)v[3] << 16);
    return r;
}
__device__ __forceinline__ u16x4 f32_to_bf4(f32x4 r) {
    u16x4 o;
    o[0] = (u16)f2bf_s(r[0]);
    o[1] = (u16)f2bf_s(r[1]);
    o[2] = (u16)f2bf_s(r[2]);
    o[3] = (u16)f2bf_s(r[3]);
    return o;
}

__device__ __forceinline__ void split8(const f32x4 a, const f32x4 b,
                                       bf16x8& hi, bf16x8& lo) {
    float x[8] = {a[0], a[1], a[2], a[3], b[0], b[1], b[2], b[3]};
#pragma unroll
    for (int j = 0; j < 8; ++j) {
        short h = f2bf_s(x[j]);
        hi[j] = h;
        lo[j] = f2bf_s(x[j] - bf2f_s(h));
    }
}

__device__ __forceinline__ f32x4 mfma3(bf16x8 ah, bf16x8 al, bf16x8 bh,
                                       bf16x8 bl, f32x4 c) {
    c = __builtin_amdgcn_mfma_f32_16x16x32_bf16(ah, bh, c, 0, 0, 0);
    c = __builtin_amdgcn_mfma_f32_16x16x32_bf16(ah, bl, c, 0, 0, 0);
    c = __builtin_amdgcn_mfma_f32_16x16x32_bf16(al, bh, c, 0, 0, 0);
    return c;
}

// ---------- prep: weights -> hi/lo bf16 (transposed); also init gcur ----------
__global__ __launch_bounds__(256) void conv_w_kernel(
    const float* __restrict__ W1, const float* __restrict__ W2,
    short* __restrict__ w1h, short* __restrict__ w1l,
    short* __restrict__ w2h, short* __restrict__ w2l,
    int* __restrict__ gcur)
{
    int i = blockIdx.x * 256 + threadIdx.x;
    if (i < NBUCKP) gcur[i] = i * CAP;
    if (i < IN_F * NH) {
        int k = i >> 6, n = i & 63;
        float v = W1[i];
        short h = f2bf_s(v);
        w1h[n * IN_F + k] = h;
        w1l[n * IN_F + k] = f2bf_s(v - bf2f_s(h));
    } else if (i < IN_F * NH + NH * NC) {
        int j = i - IN_F * NH;
        int k = j >> 4, c = j & 15;
        float v = W2[j];
        short h = f2bf_s(v);
        w2h[c * NH + k] = h;
        w2l[c * NH + k] = f2bf_s(v - bf2f_s(h));
    }
}

// ---------- encoder: z0(bf16) = relu(X@W1+b1)@W2+b2 ; hid = temp[0]*z ----------
__global__ __launch_bounds__(256) void encoder_mfma(
    const float* __restrict__ X,
    const short* __restrict__ w1h, const short* __restrict__ w1l,
    const short* __restrict__ w2h, const short* __restrict__ w2l,
    const float* __restrict__ b1, const float* __restrict__ b2,
    const float* __restrict__ temp,
    u16* __restrict__ z, float* __restrict__ hid)
{
    __shared__ float hs[128 * 68];
    const int t = threadIdx.x;
    const int wave = t >> 6, lane = t & 63;
    const int lm = lane & 15, kg = lane >> 4;
    const int wrow = blockIdx.x * 128 + wave * 32;

    int r0 = wrow + lm;       if (r0 > NN - 1) r0 = NN - 1;
    int r1 = wrow + 16 + lm;  if (r1 > NN - 1) r1 = NN - 1;
    const float* xp0 = X + (size_t)r0 * IN_F + kg * 8;
    const float* xp1 = X + (size_t)r1 * IN_F + kg * 8;
    const short* bhp = w1h + lm * IN_F + kg * 8;
    const short* blp = w1l + lm * IN_F + kg * 8;

    f32x4 acc[2][4];
#pragma unroll
    for (int m = 0; m < 2; ++m)
#pragma unroll
        for (int n = 0; n < 4; ++n) acc[m][n] = (f32x4){0.f, 0.f, 0.f, 0.f};

    for (int kb = 0; kb < IN_F; kb += 32) {
        bf16x8 ah0, al0, ah1, al1;
        {
            const f32x4* p0 = reinterpret_cast<const f32x4*>(xp0 + kb);
            split8(p0[0], p0[1], ah0, al0);
            const f32x4* p1 = reinterpret_cast<const f32x4*>(xp1 + kb);
            split8(p1[0], p1[1], ah1, al1);
        }
#pragma unroll
        for (int nt = 0; nt < 4; ++nt) {
            bf16x8 bh = *reinterpret_cast<const bf16x8*>(bhp + nt * 16 * IN_F + kb);
            bf16x8 bl = *reinterpret_cast<const bf16x8*>(blp + nt * 16 * IN_F + kb);
            acc[0][nt] = mfma3(ah0, al0, bh, bl, acc[0][nt]);
            acc[1][nt] = mfma3(ah1, al1, bh, bl, acc[1][nt]);
        }
    }

    float b1v[4];
#pragma unroll
    for (int nt = 0; nt < 4; ++nt) b1v[nt] = b1[nt * 16 + lm];
#pragma unroll
    for (int m = 0; m < 2; ++m)
#pragma unroll
        for (int nt = 0; nt < 4; ++nt)
#pragma unroll
            for (int r = 0; r < 4; ++r) {
                float v = acc[m][nt][r] + b1v[nt];
                v = v > 0.f ? v : 0.f;
                hs[(wave * 32 + m * 16 + kg * 4 + r) * 68 + nt * 16 + lm] = v;
            }

    f32x4 acc2[2];
    acc2[0] = (f32x4){0.f, 0.f, 0.f, 0.f};
    acc2[1] = (f32x4){0.f, 0.f, 0.f, 0.f};
#pragma unroll
    for (int kb = 0; kb < NH; kb += 32) {
        bf16x8 bh = *reinterpret_cast<const bf16x8*>(w2h + lm * NH + kb + kg * 8);
        bf16x8 bl = *reinterpret_cast<const bf16x8*>(w2l + lm * NH + kb + kg * 8);
#pragma unroll
        for (int m = 0; m < 2; ++m) {
            const f32x4* hp = reinterpret_cast<const f32x4*>(
                &hs[(wave * 32 + m * 16 + lm) * 68 + kb + kg * 8]);
            bf16x8 ah, al;
            split8(hp[0], hp[1], ah, al);
            acc2[m] = mfma3(ah, al, bh, bl, acc2[m]);
        }
    }

    const float b2v = b2[lm];
    const float t0 = temp[0];
#pragma unroll
    for (int m = 0; m < 2; ++m)
#pragma unroll
        for (int r = 0; r < 4; ++r) {
            int node = wrow + m * 16 + kg * 4 + r;
            if (node < NN) {
                float zv = acc2[m][r] + b2v;
                z[(size_t)node * NC + lm] = (u16)f2bf_s(zv);
                hid[(size_t)node * NC + lm] = t0 * zv;
            }
        }
}

// ---------- partition: edges -> fixed-cap bucket regions ----------
__global__ __launch_bounds__(1024) void partition_kernel(
    const int* __restrict__ src, const int* __restrict__ dst,
    const float* __restrict__ w, int* __restrict__ gcur,
    int2* __restrict__ ew)
{
    __shared__ int h[16][NBUCKP];
    __shared__ int base[NBUCKP];
    __shared__ int rnk[NBUCKP];
    const int t = threadIdx.x;
    const int wid = t >> 6;
    for (int i = t; i < 16 * NBUCKP; i += 1024) ((int*)h)[i] = 0;
    __syncthreads();
    const int s = blockIdx.x * PCHUNK;
    int e = s + PCHUNK; if (e > NE) e = NE;
    for (int i = s + t; i < e; i += 1024)
        atomicAdd(&h[wid][dst[i] >> 8], 1);
    __syncthreads();
    for (int b = t; b < NBUCKP; b += 1024) {
        int tot = 0;
#pragma unroll
        for (int ww = 0; ww < 16; ++ww) tot += h[ww][b];
        base[b] = tot ? atomicAdd(&gcur[b], tot) : 0;
        rnk[b] = 0;
    }
    __syncthreads();
    for (int i = s + t; i < e; i += 1024) {
        int d = dst[i];
        int b = d >> 8;
        int r = atomicAdd(&rnk[b], 1);
        unsigned x = (unsigned)src[i] | ((unsigned)(d & 255) << 24);
        ew[base[b] + r] = make_int2((int)x, __float_as_int(w[i]));
    }
}

// ---------- bucketfill: node-sort edges; emit srcs/wbf, rowse, degree-sorted order ----------
__global__ __launch_bounds__(256) void bucketfill_kernel(
    const int* __restrict__ gcur, const long long* __restrict__ ew,
    int* __restrict__ srcs, u16* __restrict__ wbf,
    int2* __restrict__ rowse, int* __restrict__ order)
{
    __shared__ long long buf[CAP];
    __shared__ int cnt[BSPAN], excl[BSPAN], rnk[BSPAN];
    __shared__ int dhist[128], dcur[128];
    const int b = blockIdx.x;
    const int base = b * CAP;
    int n = gcur[b] - base;
    if (n > CAP) n = CAP;
    const int t = threadIdx.x;
    cnt[t] = 0;
    order[b * BSPAN + t] = -1;          // pad; valid slots overwritten below
    if (t < 128) dhist[t] = 0;
    __syncthreads();
    for (int i = t; i < n; i += 256) {
        long long v = ew[base + i];
        buf[i] = v;
        atomicAdd(&cnt[(int)((v >> 24) & 255)], 1);
    }
    __syncthreads();
    int sv = cnt[t];
    excl[t] = sv;
    __syncthreads();
    for (int off = 1; off < 256; off <<= 1) {
        int u = (t >= off) ? excl[t - off] : 0;
        __syncthreads();
        excl[t] += u;
        __syncthreads();
    }
    int myExcl = excl[t] - sv;
    __syncthreads();
    excl[t] = myExcl;
    rnk[t] = 0;
    const int node = b * BSPAN + t;
    const bool valid = node < NN;
    if (valid) rowse[node] = make_int2(base + myExcl, sv);
    // ---- degree counting-sort -> order[] (per-bucket, ascending degree) ----
    int dg = sv > 127 ? 127 : sv;
    if (valid) atomicAdd(&dhist[dg], 1);
    __syncthreads();
    if (t < 128) dcur[t] = dhist[t];
    __syncthreads();
    for (int off = 1; off < 128; off <<= 1) {
        int u = (t >= off && t < 128) ? dcur[t - off] : 0;
        __syncthreads();
        if (t < 128) dcur[t] += u;
        __syncthreads();
    }
    if (t < 128) dcur[t] -= dhist[t];   // exclusive base per degree
    __syncthreads();
    if (valid) {
        int pos = atomicAdd(&dcur[dg], 1);
        order[b * BSPAN + pos] = node;
    }
    __syncthreads();
    for (int i = t; i < n; i += 256) {
        long long v = buf[i];
        int d = (int)((v >> 24) & 255);
        int r = atomicAdd(&rnk[d], 1);
        int pos = base + excl[d] + r;
        srcs[pos] = (int)(v & 0x00FFFFFFll);
        wbf[pos] = (u16)f2bf_s(__int_as_float((int)((unsigned long long)v >> 32)));
    }
}

// ---------- hop: 4 lanes/row via degree-sorted order; 8-edge unroll ----------
__global__ __launch_bounds__(256) void hop_kernel(
    const int* __restrict__ order,
    const int2* __restrict__ rowse, const int* __restrict__ srcs,
    const u16* __restrict__ wbf, const u16* __restrict__ in,
    u16* __restrict__ out, float* __restrict__ hid,
    const float* __restrict__ temp, int k, int last)
{
    int tid = blockIdx.x * 256 + threadIdx.x;
    int idx = tid >> 2, cg = tid & 3;
    if (idx >= NPOS) return;
    int d = order[idx];
    if (d < 0) return;
    int2 rs = rowse[d];
    int e = rs.x;
    const int e1 = rs.x + rs.y;
    const u16x4* inv = reinterpret_cast<const u16x4*>(in);
    f32x4 a0 = (f32x4){0.f, 0.f, 0.f, 0.f};
    f32x4 a1 = a0, a2 = a0, a3 = a0;

    for (; e < e1 && (e & 3); ++e) {
        float w = bf2f_u(wbf[e]);
        a0 += w * bf4_to_f32(inv[(size_t)srcs[e] * 4 + cg]);
    }
    for (; e + 7 < e1; e += 8) {
        i32x4 s4a = *reinterpret_cast<const i32x4*>(srcs + e);
        i32x4 s4b = *reinterpret_cast<const i32x4*>(srcs + e + 4);
        u16x4 w4a = *reinterpret_cast<const u16x4*>(wbf + e);
        u16x4 w4b = *reinterpret_cast<const u16x4*>(wbf + e + 4);
        u16x4 v0 = inv[(size_t)s4a[0] * 4 + cg];
        u16x4 v1 = inv[(size_t)s4a[1] * 4 + cg];
        u16x4 v2 = inv[(size_t)s4a[2] * 4 + cg];
        u16x4 v3 = inv[(size_t)s4a[3] * 4 + cg];
        u16x4 v4 = inv[(size_t)s4b[0] * 4 + cg];
        u16x4 v5 = inv[(size_t)s4b[1] * 4 + cg];
        u16x4 v6 = inv[(size_t)s4b[2] * 4 + cg];
        u16x4 v7 = inv[(size_t)s4b[3] * 4 + cg];
        a0 += bf2f_u(w4a[0]) * bf4_to_f32(v0);
        a1 += bf2f_u(w4a[1]) * bf4_to_f32(v1);
        a2 += bf2f_u(w4a[2]) * bf4_to_f32(v2);
        a3 += bf2f_u(w4a[3]) * bf4_to_f32(v3);
        a0 += bf2f_u(w4b[0]) * bf4_to_f32(v4);
        a1 += bf2f_u(w4b[1]) * bf4_to_f32(v5);
        a2 += bf2f_u(w4b[2]) * bf4_to_f32(v6);
        a3 += bf2f_u(w4b[3]) * bf4_to_f32(v7);
    }
    if (e + 3 < e1) {
        i32x4 s4a = *reinterpret_cast<const i32x4*>(srcs + e);
        u16x4 w4a = *reinterpret_cast<const u16x4*>(wbf + e);
        u16x4 v0 = inv[(size_t)s4a[0] * 4 + cg];
        u16x4 v1 = inv[(size_t)s4a[1] * 4 + cg];
        u16x4 v2 = inv[(size_t)s4a[2] * 4 + cg];
        u16x4 v3 = inv[(size_t)s4a[3] * 4 + cg];
        a0 += bf2f_u(w4a[0]) * bf4_to_f32(v0);
        a1 += bf2f_u(w4a[1]) * bf4_to_f32(v1);
        a2 += bf2f_u(w4a[2]) * bf4_to_f32(v2);
        a3 += bf2f_u(w4a[3]) * bf4_to_f32(v3);
        e += 4;
    }
    for (; e < e1; ++e) {
        float w = bf2f_u(wbf[e]);
        a0 += w * bf4_to_f32(inv[(size_t)srcs[e] * 4 + cg]);
    }

    f32x4 r = (a0 + a1) + (a2 + a3);
    size_t o = (size_t)d * 4 + cg;
    if (!last) reinterpret_cast<u16x4*>(out)[o] = f32_to_bf4(r);
    const float tk = temp[k];
    reinterpret_cast<f32x4*>(hid)[o] += tk * r;
}

// ---------- fallback (small ws): atomic scatter on row-major bf16 state ----------
__global__ __launch_bounds__(256) void spmm_atomic_bf16(
    const int* __restrict__ src, const int* __restrict__ dst,
    const float* __restrict__ w, const u16* __restrict__ in,
    float* __restrict__ outf)
{
    int tid = blockIdx.x * 256 + threadIdx.x;
    int e = tid >> 4, c = tid & 15;
    if (e >= NE) return;
    float v = bf2f_u(in[(size_t)src[e] * NC + c]);
    atomicAdd(&outf[(size_t)dst[e] * NC + c], w[e] * v);
}
__global__ __launch_bounds__(256) void axpy_quant_kernel(
    float* __restrict__ hid, const float* __restrict__ outf,
    u16* __restrict__ nextb, const float* __restrict__ temp, int k)
{
    int i = blockIdx.x * 256 + threadIdx.x;
    if (i < NN * NC) {
        float r = outf[i];
        hid[i] += temp[k] * r;
        nextb[i] = (u16)f2bf_s(r);
    }
}

extern "C" void kernel_launch(void* const* d_in, const int* in_sizes, int n_in,
                              void* d_out, int out_size, void* d_ws, size_t ws_size,
                              hipStream_t stream)
{
    const float* feature = (const float*)d_in[0];
    const float* W1      = (const float*)d_in[1];
    const float* b1      = (const float*)d_in[2];
    const float* W2      = (const float*)d_in[3];
    const float* b2      = (const float*)d_in[4];
    const int*   edges   = (const int*)d_in[5];
    const float* norm_A  = (const float*)d_in[6];
    const float* temp    = (const float*)d_in[7];
    const int* src = edges;
    const int* dst = edges + NE;
    float* hid = (float*)d_out;

    char* p = (char*)d_ws;
    size_t off = 0;
    auto carve = [&](size_t bytes) {
        void* r = p + off;
        off += (bytes + 255) & ~(size_t)255;
        return r;
    };
    u16*   zkA   = (u16*)carve((size_t)NN * NC * 2);
    u16*   zkB   = (u16*)carve((size_t)NN * NC * 2);
    short* w1h   = (short*)carve((size_t)IN_F * NH * 2);
    short* w1l   = (short*)carve((size_t)IN_F * NH * 2);
    short* w2h   = (short*)carve((size_t)NH * NC * 2);
    short* w2l   = (short*)carve((size_t)NH * NC * 2);
    int*   gcur  = (int*)carve((size_t)NBUCKP * 4);
    int2*  rowse = (int2*)carve((size_t)NN * 8);
    int*   order = (int*)carve((size_t)NPOS * 4);
    int2*  ew    = (int2*)carve((size_t)NBUCKC * CAP * 8);
    int*   srcs  = (int*)carve((size_t)NBUCKC * CAP * 4);
    u16*   wbf   = (u16*)carve((size_t)NBUCKC * CAP * 2);
    const bool useCSR = (off <= ws_size);

    conv_w_kernel<<<(IN_F * NH + NH * NC + 255) / 256, 256, 0, stream>>>(
        W1, W2, w1h, w1l, w2h, w2l, gcur);
    encoder_mfma<<<(NN + 127) / 128, 256, 0, stream>>>(
        feature, w1h, w1l, w2h, w2l, b1, b2, temp, zkA, hid);

    if (useCSR) {
        partition_kernel<<<PART_BLOCKS, 1024, 0, stream>>>(src, dst, norm_A,
                                                           gcur, ew);
        bucketfill_kernel<<<NBUCKC, 256, 0, stream>>>(
            gcur, (const long long*)ew, srcs, wbf, rowse, order);

        const int hopGrid = (NPOS * 4) / 256;        // 1564
        u16* cur = zkA;
        u16* nxt = zkB;
        for (int k = 1; k <= K_HOPS; ++k) {
            hop_kernel<<<hopGrid, 256, 0, stream>>>(
                order, rowse, srcs, wbf, cur, nxt, hid, temp, k, k == K_HOPS);
            u16* t2 = cur; cur = nxt; nxt = t2;
        }
    } else {
        float* outf = (float*)ew;
        const int spmmGrid = (NE * NC + 255) / 256;
        const int vecGrid  = (NN * NC + 255) / 256;
        u16* cur = zkA; u16* nxt = zkB;
        for (int k = 1; k <= K_HOPS; ++k) {
            (void)hipMemsetAsync(outf, 0, (size_t)NN * NC * 4, stream);
            spmm_atomic_bf16<<<spmmGrid, 256, 0, stream>>>(src, dst, norm_A,
                                                           cur, outf);
            axpy_quant_kernel<<<vecGrid, 256, 0, stream>>>(hid, outf, nxt,
                                                           temp, k);
            u16* t2 = cur; cur = nxt; nxt = t2;
        }
    }
}

// Round 15
// 520.142 us; speedup vs baseline: 1.1798x; 1.1798x over previous
//
#include <hip/hip_runtime.h>
#include <hip/hip_bf16.h>

#define NN 100000
#define NE 3200000
#define IN_F 512
#define NH 64
#define NC 16
#define K_HOPS 10

#define BSPAN 256
#define NBUCKC ((NN + BSPAN - 1) / BSPAN)   // 391
#define NBUCKP 512
#define CAP 9216
#define PART_BLOCKS 256
#define PCHUNK ((NE + PART_BLOCKS - 1) / PART_BLOCKS)  // 12500

typedef short bf16x8 __attribute__((ext_vector_type(8)));
typedef float f32x4 __attribute__((ext_vector_type(4)));
typedef unsigned short u16;
typedef u16 u16x4 __attribute__((ext_vector_type(4)));

__device__ __forceinline__ short f2bf_s(float x) {
    __hip_bfloat16 b = __float2bfloat16(x);
    return *reinterpret_cast<short*>(&b);
}
__device__ __forceinline__ float bf2f_s(short s) {
    __hip_bfloat16 b = *reinterpret_cast<__hip_bfloat16*>(&s);
    return __bfloat162float(b);
}
__device__ __forceinline__ float bf2f_u(u16 s) {
    return __uint_as_float((unsigned)s << 16);
}
__device__ __forceinline__ f32x4 bf4_to_f32(u16x4 v) {
    f32x4 r;
    r[0] = __uint_as_float((unsigned)v[0] << 16);
    r[1] = __uint_as_float((unsigned)v[1] << 16);
    r[2] = __uint_as_float((unsigned)v[2] << 16);
    r[3] = __uint_as_float((unsigned)v[3] << 16);
    return r;
}
__device__ __forceinline__ u16x4 f32_to_bf4(f32x4 r) {
    u16x4 o;
    o[0] = (u16)f2bf_s(r[0]);
    o[1] = (u16)f2bf_s(r[1]);
    o[2] = (u16)f2bf_s(r[2]);
    o[3] = (u16)f2bf_s(r[3]);
    return o;
}

__device__ __forceinline__ void split8(const f32x4 a, const f32x4 b,
                                       bf16x8& hi, bf16x8& lo) {
    float x[8] = {a[0], a[1], a[2], a[3], b[0], b[1], b[2], b[3]};
#pragma unroll
    for (int j = 0; j < 8; ++j) {
        short h = f2bf_s(x[j]);
        hi[j] = h;
        lo[j] = f2bf_s(x[j] - bf2f_s(h));
    }
}

__device__ __forceinline__ f32x4 mfma3(bf16x8 ah, bf16x8 al, bf16x8 bh,
                                       bf16x8 bl, f32x4 c) {
    c = __builtin_amdgcn_mfma_f32_16x16x32_bf16(ah, bh, c, 0, 0, 0);
    c = __builtin_amdgcn_mfma_f32_16x16x32_bf16(ah, bl, c, 0, 0, 0);
    c = __builtin_amdgcn_mfma_f32_16x16x32_bf16(al, bh, c, 0, 0, 0);
    return c;
}

// ---------- prep: weights -> hi/lo bf16 (transposed); also init gcur ----------
__global__ __launch_bounds__(256) void conv_w_kernel(
    const float* __restrict__ W1, const float* __restrict__ W2,
    short* __restrict__ w1h, short* __restrict__ w1l,
    short* __restrict__ w2h, short* __restrict__ w2l,
    int* __restrict__ gcur)
{
    int i = blockIdx.x * 256 + threadIdx.x;
    if (i < NBUCKP) gcur[i] = i * CAP;
    if (i < IN_F * NH) {
        int k = i >> 6, n = i & 63;
        float v = W1[i];
        short h = f2bf_s(v);
        w1h[n * IN_F + k] = h;
        w1l[n * IN_F + k] = f2bf_s(v - bf2f_s(h));
    } else if (i < IN_F * NH + NH * NC) {
        int j = i - IN_F * NH;
        int k = j >> 4, c = j & 15;
        float v = W2[j];
        short h = f2bf_s(v);
        w2h[c * NH + k] = h;
        w2l[c * NH + k] = f2bf_s(v - bf2f_s(h));
    }
}

// ---------- encoder: z0(bf16 row-major) = relu(X@W1+b1)@W2+b2 ; hid = temp[0]*z ----------
__global__ __launch_bounds__(256) void encoder_mfma(
    const float* __restrict__ X,
    const short* __restrict__ w1h, const short* __restrict__ w1l,
    const short* __restrict__ w2h, const short* __restrict__ w2l,
    const float* __restrict__ b1, const float* __restrict__ b2,
    const float* __restrict__ temp,
    u16* __restrict__ z, float* __restrict__ hid)
{
    __shared__ float hs[128 * 68];
    const int t = threadIdx.x;
    const int wave = t >> 6, lane = t & 63;
    const int lm = lane & 15, kg = lane >> 4;
    const int wrow = blockIdx.x * 128 + wave * 32;

    int r0 = wrow + lm;       if (r0 > NN - 1) r0 = NN - 1;
    int r1 = wrow + 16 + lm;  if (r1 > NN - 1) r1 = NN - 1;
    const float* xp0 = X + (size_t)r0 * IN_F + kg * 8;
    const float* xp1 = X + (size_t)r1 * IN_F + kg * 8;
    const short* bhp = w1h + lm * IN_F + kg * 8;
    const short* blp = w1l + lm * IN_F + kg * 8;

    f32x4 acc[2][4];
#pragma unroll
    for (int m = 0; m < 2; ++m)
#pragma unroll
        for (int n = 0; n < 4; ++n) acc[m][n] = (f32x4){0.f, 0.f, 0.f, 0.f};

    for (int kb = 0; kb < IN_F; kb += 32) {
        bf16x8 ah0, al0, ah1, al1;
        {
            const f32x4* p0 = reinterpret_cast<const f32x4*>(xp0 + kb);
            split8(p0[0], p0[1], ah0, al0);
            const f32x4* p1 = reinterpret_cast<const f32x4*>(xp1 + kb);
            split8(p1[0], p1[1], ah1, al1);
        }
#pragma unroll
        for (int nt = 0; nt < 4; ++nt) {
            bf16x8 bh = *reinterpret_cast<const bf16x8*>(bhp + nt * 16 * IN_F + kb);
            bf16x8 bl = *reinterpret_cast<const bf16x8*>(blp + nt * 16 * IN_F + kb);
            acc[0][nt] = mfma3(ah0, al0, bh, bl, acc[0][nt]);
            acc[1][nt] = mfma3(ah1, al1, bh, bl, acc[1][nt]);
        }
    }

    float b1v[4];
#pragma unroll
    for (int nt = 0; nt < 4; ++nt) b1v[nt] = b1[nt * 16 + lm];
#pragma unroll
    for (int m = 0; m < 2; ++m)
#pragma unroll
        for (int nt = 0; nt < 4; ++nt)
#pragma unroll
            for (int r = 0; r < 4; ++r) {
                float v = acc[m][nt][r] + b1v[nt];
                v = v > 0.f ? v : 0.f;
                hs[(wave * 32 + m * 16 + kg * 4 + r) * 68 + nt * 16 + lm] = v;
            }

    f32x4 acc2[2];
    acc2[0] = (f32x4){0.f, 0.f, 0.f, 0.f};
    acc2[1] = (f32x4){0.f, 0.f, 0.f, 0.f};
#pragma unroll
    for (int kb = 0; kb < NH; kb += 32) {
        bf16x8 bh = *reinterpret_cast<const bf16x8*>(w2h + lm * NH + kb + kg * 8);
        bf16x8 bl = *reinterpret_cast<const bf16x8*>(w2l + lm * NH + kb + kg * 8);
#pragma unroll
        for (int m = 0; m < 2; ++m) {
            const f32x4* hp = reinterpret_cast<const f32x4*>(
                &hs[(wave * 32 + m * 16 + lm) * 68 + kb + kg * 8]);
            bf16x8 ah, al;
            split8(hp[0], hp[1], ah, al);
            acc2[m] = mfma3(ah, al, bh, bl, acc2[m]);
        }
    }

    const float b2v = b2[lm];
    const float t0 = temp[0];
#pragma unroll
    for (int m = 0; m < 2; ++m)
#pragma unroll
        for (int r = 0; r < 4; ++r) {
            int node = wrow + m * 16 + kg * 4 + r;
            if (node < NN) {
                float zv = acc2[m][r] + b2v;
                z[(size_t)node * NC + lm] = (u16)f2bf_s(zv);
                hid[(size_t)node * NC + lm] = t0 * zv;
            }
        }
}

// ---------- partition: edges -> fixed-cap bucket regions ----------
__global__ __launch_bounds__(1024) void partition_kernel(
    const int* __restrict__ src, const int* __restrict__ dst,
    const float* __restrict__ w, int* __restrict__ gcur,
    int2* __restrict__ ew)
{
    __shared__ int h[16][NBUCKP];
    __shared__ int base[NBUCKP];
    __shared__ int rnk[NBUCKP];
    const int t = threadIdx.x;
    const int wid = t >> 6;
    for (int i = t; i < 16 * NBUCKP; i += 1024) ((int*)h)[i] = 0;
    __syncthreads();
    const int s = blockIdx.x * PCHUNK;
    int e = s + PCHUNK; if (e > NE) e = NE;
    for (int i = s + t; i < e; i += 1024)
        atomicAdd(&h[wid][dst[i] >> 8], 1);
    __syncthreads();
    for (int b = t; b < NBUCKP; b += 1024) {
        int tot = 0;
#pragma unroll
        for (int ww = 0; ww < 16; ++ww) tot += h[ww][b];
        base[b] = tot ? atomicAdd(&gcur[b], tot) : 0;
        rnk[b] = 0;
    }
    __syncthreads();
    for (int i = s + t; i < e; i += 1024) {
        int d = dst[i];
        int b = d >> 8;
        int r = atomicAdd(&rnk[b], 1);
        unsigned x = (unsigned)src[i] | ((unsigned)(d & 255) << 24);
        ew[base[b] + r] = make_int2((int)x, __float_as_int(w[i]));
    }
}

// ---------- bucketfill: node-sort edges within bucket; emit split srcs/wbf ----------
__global__ __launch_bounds__(256) void bucketfill_kernel(
    const int* __restrict__ gcur, const long long* __restrict__ ew,
    int* __restrict__ srcs, u16* __restrict__ wbf,
    int2* __restrict__ rowse)
{
    __shared__ long long buf[CAP];
    __shared__ int cnt[BSPAN], excl[BSPAN], rnk[BSPAN];
    const int b = blockIdx.x;
    const int base = b * CAP;
    int n = gcur[b] - base;
    if (n > CAP) n = CAP;
    const int t = threadIdx.x;
    cnt[t] = 0;
    __syncthreads();
    for (int i = t; i < n; i += 256) {
        long long v = ew[base + i];
        buf[i] = v;
        atomicAdd(&cnt[(int)((v >> 24) & 255)], 1);
    }
    __syncthreads();
    int sv = cnt[t];
    excl[t] = sv;
    __syncthreads();
    for (int off = 1; off < 256; off <<= 1) {
        int u = (t >= off) ? excl[t - off] : 0;
        __syncthreads();
        excl[t] += u;
        __syncthreads();
    }
    int myExcl = excl[t] - sv;
    __syncthreads();
    excl[t] = myExcl;
    rnk[t] = 0;
    int node = b * BSPAN + t;
    if (node < NN) rowse[node] = make_int2(base + myExcl, sv);
    __syncthreads();
    for (int i = t; i < n; i += 256) {
        long long v = buf[i];
        int d = (int)((v >> 24) & 255);
        int r = atomicAdd(&rnk[d], 1);
        int pos = base + excl[d] + r;
        srcs[pos] = (int)(v & 0x00FFFFFFll);
        wbf[pos] = (u16)f2bf_s(__int_as_float((int)((unsigned long long)v >> 32)));
    }
}

// ---------- hop: 4 lanes/row; vectorized stream loads; gathers coalesce 32B ----------
__global__ __launch_bounds__(256) void hop_kernel(
    const int2* __restrict__ rowse, const int* __restrict__ srcs,
    const u16* __restrict__ wbf, const u16* __restrict__ in,
    u16* __restrict__ out, float* __restrict__ hid,
    const float* __restrict__ temp, int k, int last)
{
    int tid = blockIdx.x * 256 + threadIdx.x;
    int d = tid >> 2, cg = tid & 3;
    if (d >= NN) return;
    int2 rs = rowse[d];
    int e = rs.x;
    const int e1 = rs.x + rs.y;
    const u16x4* inv = reinterpret_cast<const u16x4*>(in);
    f32x4 a0 = (f32x4){0.f, 0.f, 0.f, 0.f};
    f32x4 a1 = a0, a2 = a0, a3 = a0;

    // head: align e to 4
    for (; e < e1 && (e & 3); ++e) {
        float w = bf2f_u(wbf[e]);
        a0 += w * bf4_to_f32(inv[(size_t)srcs[e] * 4 + cg]);
    }
    // body: 8 edges per iteration (two int4 + two u16x4 stream loads)
    for (; e + 7 < e1; e += 8) {
        int4 s4a = *reinterpret_cast<const int4*>(srcs + e);
        int4 s4b = *reinterpret_cast<const int4*>(srcs + e + 4);
        u16x4 w4a = *reinterpret_cast<const u16x4*>(wbf + e);
        u16x4 w4b = *reinterpret_cast<const u16x4*>(wbf + e + 4);
        u16x4 v0 = inv[(size_t)s4a.x * 4 + cg];
        u16x4 v1 = inv[(size_t)s4a.y * 4 + cg];
        u16x4 v2 = inv[(size_t)s4a.z * 4 + cg];
        u16x4 v3 = inv[(size_t)s4a.w * 4 + cg];
        u16x4 v4 = inv[(size_t)s4b.x * 4 + cg];
        u16x4 v5 = inv[(size_t)s4b.y * 4 + cg];
        u16x4 v6 = inv[(size_t)s4b.z * 4 + cg];
        u16x4 v7 = inv[(size_t)s4b.w * 4 + cg];
        a0 += bf2f_u(w4a[0]) * bf4_to_f32(v0);
        a1 += bf2f_u(w4a[1]) * bf4_to_f32(v1);
        a2 += bf2f_u(w4a[2]) * bf4_to_f32(v2);
        a3 += bf2f_u(w4a[3]) * bf4_to_f32(v3);
        a0 += bf2f_u(w4b[0]) * bf4_to_f32(v4);
        a1 += bf2f_u(w4b[1]) * bf4_to_f32(v5);
        a2 += bf2f_u(w4b[2]) * bf4_to_f32(v6);
        a3 += bf2f_u(w4b[3]) * bf4_to_f32(v7);
    }
    // mid: 4 edges
    if (e + 3 < e1) {
        int4 s4a = *reinterpret_cast<const int4*>(srcs + e);
        u16x4 w4a = *reinterpret_cast<const u16x4*>(wbf + e);
        u16x4 v0 = inv[(size_t)s4a.x * 4 + cg];
        u16x4 v1 = inv[(size_t)s4a.y * 4 + cg];
        u16x4 v2 = inv[(size_t)s4a.z * 4 + cg];
        u16x4 v3 = inv[(size_t)s4a.w * 4 + cg];
        a0 += bf2f_u(w4a[0]) * bf4_to_f32(v0);
        a1 += bf2f_u(w4a[1]) * bf4_to_f32(v1);
        a2 += bf2f_u(w4a[2]) * bf4_to_f32(v2);
        a3 += bf2f_u(w4a[3]) * bf4_to_f32(v3);
        e += 4;
    }
    // tail
    for (; e < e1; ++e) {
        float w = bf2f_u(wbf[e]);
        a0 += w * bf4_to_f32(inv[(size_t)srcs[e] * 4 + cg]);
    }

    f32x4 r = (a0 + a1) + (a2 + a3);
    size_t o = (size_t)d * 4 + cg;
    if (!last) reinterpret_cast<u16x4*>(out)[o] = f32_to_bf4(r);
    const float tk = temp[k];
    reinterpret_cast<f32x4*>(hid)[o] += tk * r;
}

// ---------- fallback (small ws): atomic scatter on row-major bf16 state ----------
__global__ __launch_bounds__(256) void spmm_atomic_bf16(
    const int* __restrict__ src, const int* __restrict__ dst,
    const float* __restrict__ w, const u16* __restrict__ in,
    float* __restrict__ outf)
{
    int tid = blockIdx.x * 256 + threadIdx.x;
    int e = tid >> 4, c = tid & 15;
    if (e >= NE) return;
    float v = bf2f_u(in[(size_t)src[e] * NC + c]);
    atomicAdd(&outf[(size_t)dst[e] * NC + c], w[e] * v);
}
__global__ __launch_bounds__(256) void axpy_quant_kernel(
    float* __restrict__ hid, const float* __restrict__ outf,
    u16* __restrict__ nextb, const float* __restrict__ temp, int k)
{
    int i = blockIdx.x * 256 + threadIdx.x;
    if (i < NN * NC) {
        float r = outf[i];
        hid[i] += temp[k] * r;
        nextb[i] = (u16)f2bf_s(r);
    }
}

extern "C" void kernel_launch(void* const* d_in, const int* in_sizes, int n_in,
                              void* d_out, int out_size, void* d_ws, size_t ws_size,
                              hipStream_t stream)
{
    const float* feature = (const float*)d_in[0];
    const float* W1      = (const float*)d_in[1];
    const float* b1      = (const float*)d_in[2];
    const float* W2      = (const float*)d_in[3];
    const float* b2      = (const float*)d_in[4];
    const int*   edges   = (const int*)d_in[5];
    const float* norm_A  = (const float*)d_in[6];
    const float* temp    = (const float*)d_in[7];
    const int* src = edges;
    const int* dst = edges + NE;
    float* hid = (float*)d_out;

    char* p = (char*)d_ws;
    size_t off = 0;
    auto carve = [&](size_t bytes) {
        void* r = p + off;
        off += (bytes + 255) & ~(size_t)255;
        return r;
    };
    u16*   zkA   = (u16*)carve((size_t)NN * NC * 2);
    u16*   zkB   = (u16*)carve((size_t)NN * NC * 2);
    short* w1h   = (short*)carve((size_t)IN_F * NH * 2);
    short* w1l   = (short*)carve((size_t)IN_F * NH * 2);
    short* w2h   = (short*)carve((size_t)NH * NC * 2);
    short* w2l   = (short*)carve((size_t)NH * NC * 2);
    int*   gcur  = (int*)carve((size_t)NBUCKP * 4);
    int2*  rowse = (int2*)carve((size_t)NN * 8);
    int2*  ew    = (int2*)carve((size_t)NBUCKC * CAP * 8);   // 28.8 MB staging
    int*   srcs  = (int*)carve((size_t)NBUCKC * CAP * 4);    // 14.4 MB
    u16*   wbf   = (u16*)carve((size_t)NBUCKC * CAP * 2);    // 7.2 MB
    const bool useCSR = (off <= ws_size);

    conv_w_kernel<<<(IN_F * NH + NH * NC + 255) / 256, 256, 0, stream>>>(
        W1, W2, w1h, w1l, w2h, w2l, gcur);
    encoder_mfma<<<(NN + 127) / 128, 256, 0, stream>>>(
        feature, w1h, w1l, w2h, w2l, b1, b2, temp, zkA, hid);

    if (useCSR) {
        partition_kernel<<<PART_BLOCKS, 1024, 0, stream>>>(src, dst, norm_A,
                                                           gcur, ew);
        bucketfill_kernel<<<NBUCKC, 256, 0, stream>>>(
            gcur, (const long long*)ew, srcs, wbf, rowse);

        const int hopGrid = (NN * 4 + 255) / 256;    // 1563
        u16* cur = zkA;
        u16* nxt = zkB;
        for (int k = 1; k <= K_HOPS; ++k) {
            hop_kernel<<<hopGrid, 256, 0, stream>>>(
                rowse, srcs, wbf, cur, nxt, hid, temp, k, k == K_HOPS);
            u16* t2 = cur; cur = nxt; nxt = t2;
        }
    } else {
        float* outf = (float*)ew;
        const int spmmGrid = (NE * NC + 255) / 256;
        const int vecGrid  = (NN * NC + 255) / 256;
        u16* cur = zkA; u16* nxt = zkB;
        for (int k = 1; k <= K_HOPS; ++k) {
            (void)hipMemsetAsync(outf, 0, (size_t)NN * NC * 4, stream);
            spmm_atomic_bf16<<<spmmGrid, 256, 0, stream>>>(src, dst, norm_A,
                                                           cur, outf);
            axpy_quant_kernel<<<vecGrid, 256, 0, stream>>>(hid, outf, nxt,
                                                           temp, k);
            u16* t2 = cur; cur = nxt; nxt = t2;
        }
    }
}